// Round 12
// baseline (245.001 us; speedup 1.0000x reference)
//
#include <hip/hip_runtime.h>

#define B_ 2
#define L_ 2048
#define D_ 512
#define H_ 8
#define DK 64
#define S_ 10240
#define SCALE 0.125f

#define QSZ (4096 * 512)  // B_*L_*D_ elements

typedef _Float16 f16;
typedef __attribute__((ext_vector_type(8))) _Float16 f16x8;
typedef __attribute__((ext_vector_type(4))) float f32x4;

#define AS1 __attribute__((address_space(1)))
#define AS3 __attribute__((address_space(3)))

// ---------------------------------------------------------------------------
// prep: split x -> xh/xl, split Wq|Wk -> wh/wl + biascat, xbar_c partials,
// zero counts + gate flags (hist runs inside projqk, after).
// ---------------------------------------------------------------------------
__global__ __launch_bounds__(256) void prep_kernel(
    const float* __restrict__ x,
    const float* __restrict__ Wq, const float* __restrict__ Wk,
    const float* __restrict__ bq, const float* __restrict__ bk,
    const int* __restrict__ samp,
    f16* __restrict__ xh, f16* __restrict__ xl,
    f16* __restrict__ wh, f16* __restrict__ wl,
    float* __restrict__ biascat, int* __restrict__ counts,
    float* __restrict__ xbc_part, int* __restrict__ flags)
{
    const int bid = blockIdx.x;
    const int t = threadIdx.x;
    if (bid < 1024) {
        const size_t i0 = ((size_t)bid * 256 + t) * 8;
        const float4 a = *(const float4*)&x[i0];
        const float4 b = *(const float4*)&x[i0 + 4];
        const float vals[8] = {a.x, a.y, a.z, a.w, b.x, b.y, b.z, b.w};
        union { f16 h[8]; uint4 u; } H, Lo;
#pragma unroll
        for (int j = 0; j < 8; j++) {
            const f16 hh = (f16)vals[j];
            H.h[j] = hh;
            Lo.h[j] = (f16)(vals[j] - (float)hh);
        }
        *(uint4*)&xh[i0] = H.u;
        *(uint4*)&xl[i0] = Lo.u;
    } else if (bid < 1280) {
        const size_t i0 = ((size_t)(bid - 1024) * 256 + t) * 8;
        const float* src = (i0 < (size_t)512 * 512) ? Wq + i0
                                                    : Wk + (i0 - (size_t)512 * 512);
        const float4 a = *(const float4*)&src[0];
        const float4 b = *(const float4*)&src[4];
        const float vals[8] = {a.x, a.y, a.z, a.w, b.x, b.y, b.z, b.w};
        union { f16 h[8]; uint4 u; } H, Lo;
#pragma unroll
        for (int j = 0; j < 8; j++) {
            const f16 hh = (f16)vals[j];
            H.h[j] = hh;
            Lo.h[j] = (f16)(vals[j] - (float)hh);
        }
        *(uint4*)&wh[i0] = H.u;
        *(uint4*)&wl[i0] = Lo.u;
        if (bid == 1024)
            for (int e = t; e < 1024; e += 256)
                biascat[e] = (e < 512) ? bq[e] : bk[e - 512];
    } else if (bid < 1344) {
        // xbar_c partials: sum of x rows over a 320-sample slice
        const int p = bid - 1280;            // 0..63
        const int bb = p >> 5, chunk = p & 31;
        const int s0 = chunk * 320;
        float ax = 0.f, ay = 0.f;
        const float* xb = x + (size_t)bb * L_ * D_ + t * 2;
        for (int i = 0; i < 320; i++) {
            const int j = samp[s0 + i];
            const float2 v = *(const float2*)(xb + (size_t)j * D_);
            ax += v.x; ay += v.y;
        }
        float2 st; st.x = ax; st.y = ay;
        *(float2*)&xbc_part[((size_t)(bb * 32 + chunk)) * 512 + t * 2] = st;
    } else {
        // zero counts (2 blocks x 256 x int4) + gate flags
        int4 z; z.x = 0; z.y = 0; z.z = 0; z.w = 0;
        ((int4*)counts)[(bid - 1344) * 256 + t] = z;
        if (bid == 1344 && t == 0) { flags[0] = 0; flags[1] = 0; }
    }
}

// ---------------------------------------------------------------------------
// q,k projections via split-f16 MFMA GEMM: [4096 x 512] . [512 x 1024]^T
// Staging via global_load_lds with pre-swizzled source (m97 structure).
// Blocks 256..271 (tail-scheduled): kbar = xbar_c . Wk_h + bk_h, + histogram.
// ---------------------------------------------------------------------------
__global__ __launch_bounds__(256) void projqk_kernel(
    const f16* __restrict__ xh, const f16* __restrict__ xl,
    const f16* __restrict__ wh, const f16* __restrict__ wl,
    const float* __restrict__ biascat,
    const float* __restrict__ xbc_part, const float* __restrict__ Wk,
    const float* __restrict__ bk, const int* __restrict__ samp,
    int* __restrict__ counts, float* __restrict__ kbar,
    f16* __restrict__ qh, f16* __restrict__ ql,
    f16* __restrict__ kh, f16* __restrict__ kl)
{
    const int bid = blockIdx.x;
    const int t = threadIdx.x;

    __shared__ __align__(16) f16 lds[4 * 128 * 64];   // 64 KB

    if (bid >= 256) {
        // ---- kbar + histogram block (runs in the tail on freed CUs) ----
        const int bh = bid - 256;
        const int b = bh >> 3, h = bh & 7;
        float* xc = (float*)lds;

        for (int i = bh * 640 + t; i < (bh + 1) * 640; i += 256)
            atomicAdd(&counts[samp[i]], 1);

        float ax = 0.f, ay = 0.f;
#pragma unroll
        for (int p = 0; p < 32; p++) {
            const float2 v = *(const float2*)&xbc_part[((size_t)(b * 32 + p)) * 512 + t * 2];
            ax += v.x; ay += v.y;
        }
        xc[t * 2]     = ax * (1.0f / (float)S_);
        xc[t * 2 + 1] = ay * (1.0f / (float)S_);
        __syncthreads();

        const int row = t >> 2, quarter = t & 3;
        const float* wr = Wk + (size_t)(h * 64 + row) * 512 + quarter * 128;
        float s = 0.f;
#pragma unroll 8
        for (int d = 0; d < 32; d++) {
            const float4 w4 = *(const float4*)&wr[d * 4];
            const int xo = quarter * 128 + d * 4;
            s += w4.x * xc[xo] + w4.y * xc[xo + 1] + w4.z * xc[xo + 2] + w4.w * xc[xo + 3];
        }
        s += __shfl_xor(s, 1);
        s += __shfl_xor(s, 2);
        if (quarter == 0) kbar[bh * 64 + row] = s + bk[h * 64 + row];
        return;
    }

    // ---- GEMM block ----
    const int n0 = (bid & 31) * 128;   // rows (tokens)
    const int e0 = (bid >> 5) * 128;   // cols (proj dims, 0..1023)

    f16* ash = lds;
    f16* asl = lds + 8192;
    f16* bsh = lds + 16384;
    f16* bsl = lds + 24576;

    const int lane = t & 63, wid = t >> 6;
    const int wr = wid >> 1, wc = wid & 1;
    const int lrow = lane & 15, lk = lane >> 4;
    const int srw = lane >> 3;               // row within 8-row group
    const int scg = (lane & 7) ^ srw;        // pre-swizzled global col chunk

    f32x4 acc[4][4];
#pragma unroll
    for (int i = 0; i < 4; i++)
#pragma unroll
        for (int j = 0; j < 4; j++)
#pragma unroll
            for (int r = 0; r < 4; r++) acc[i][j][r] = 0.f;

    for (int kt = 0; kt < 8; kt++) {
        __syncthreads();
#pragma unroll
        for (int i_ = 0; i_ < 4; i_++) {
            const int chunk = wid * 4 + i_;
            const int row = chunk * 8 + srw;
            const size_t goa = (size_t)(n0 + row) * 512 + kt * 64 + scg * 8;
            const size_t gob = (size_t)(e0 + row) * 512 + kt * 64 + scg * 8;
            __builtin_amdgcn_global_load_lds((const AS1 void*)(xh + goa),
                                             (AS3 void*)(&ash[chunk * 512]), 16, 0, 0);
            __builtin_amdgcn_global_load_lds((const AS1 void*)(xl + goa),
                                             (AS3 void*)(&asl[chunk * 512]), 16, 0, 0);
            __builtin_amdgcn_global_load_lds((const AS1 void*)(wh + gob),
                                             (AS3 void*)(&bsh[chunk * 512]), 16, 0, 0);
            __builtin_amdgcn_global_load_lds((const AS1 void*)(wl + gob),
                                             (AS3 void*)(&bsl[chunk * 512]), 16, 0, 0);
        }
        __syncthreads();

#pragma unroll
        for (int kk = 0; kk < 2; kk++) {
            f16x8 ah[4], al[4], bh_[4], bl_[4];
#pragma unroll
            for (int lt = 0; lt < 4; lt++) {
                const int row = wr * 64 + lt * 16 + lrow;
                const int cs = (kk * 4 + lk) ^ (row & 7);
                const int o = row * 64 + cs * 8;
                ah[lt] = *(const f16x8*)&ash[o];
                al[lt] = *(const f16x8*)&asl[o];
            }
#pragma unroll
            for (int jt = 0; jt < 4; jt++) {
                const int row = wc * 64 + jt * 16 + lrow;
                const int cs = (kk * 4 + lk) ^ (row & 7);
                const int o = row * 64 + cs * 8;
                bh_[jt] = *(const f16x8*)&bsh[o];
                bl_[jt] = *(const f16x8*)&bsl[o];
            }
#pragma unroll
            for (int lt = 0; lt < 4; lt++)
#pragma unroll
                for (int jt = 0; jt < 4; jt++) {
                    acc[lt][jt] = __builtin_amdgcn_mfma_f32_16x16x32_f16(
                        ah[lt], bh_[jt], acc[lt][jt], 0, 0, 0);
                    acc[lt][jt] = __builtin_amdgcn_mfma_f32_16x16x32_f16(
                        ah[lt], bl_[jt], acc[lt][jt], 0, 0, 0);
                    acc[lt][jt] = __builtin_amdgcn_mfma_f32_16x16x32_f16(
                        al[lt], bh_[jt], acc[lt][jt], 0, 0, 0);
                }
        }
    }

    // Epilogue: bias add, split to hi/lo, LDS transpose for coalesced stores.
    const int PSTR = 72;
    f16* tile = lds + wid * 64 * PSTR;
    const int ebase = e0 + wc * 64;
    const bool isQ = ((bid >> 5) < 4);
    const int colbase = ((bid >> 5) & 3) * 128;

#pragma unroll
    for (int round = 0; round < 2; round++) {
        __syncthreads();
#pragma unroll
        for (int jt = 0; jt < 4; jt++) {
            const float bval = biascat[ebase + jt * 16 + lrow];
#pragma unroll
            for (int lt = 0; lt < 4; lt++)
#pragma unroll
                for (int r = 0; r < 4; r++) {
                    const float y = acc[lt][jt][r] + bval;
                    const f16 hi = (f16)y;
                    const f16 val = (round == 0) ? hi : (f16)(y - (float)hi);
                    tile[(lt * 16 + lk * 4 + r) * PSTR + jt * 16 + lrow] = val;
                }
        }
        __syncthreads();
        f16* dst = isQ ? ((round == 0) ? qh : ql) : ((round == 0) ? kh : kl);
        for (int i = t; i < 2048; i += 256) {
            const int w = i >> 9, rem = i & 511, row = rem >> 3, c = rem & 7;
            const int n = n0 + (w >> 1) * 64 + row;
            const int col = colbase + (w & 1) * 64 + c * 8;
            *(uint4*)&dst[(size_t)n * 512 + col] =
                *(const uint4*)&lds[w * 64 * PSTR + row * PSTR + c * 8];
        }
    }
}

// ---------------------------------------------------------------------------
// mstat: per (l-chunk128, bh, j-half) block. q frags in registers, K staged
// HBM->LDS via global_load_lds, double-buffered.  Fused block argmax.
// ---------------------------------------------------------------------------
__global__ __launch_bounds__(256, 2) void mstat_kernel(
    const f16* __restrict__ qh, const f16* __restrict__ ql,
    const f16* __restrict__ kh, const f16* __restrict__ kl,
    const int* __restrict__ counts, const float* __restrict__ kbar,
    float* __restrict__ bestv, int* __restrict__ besti)
{
    const int id = blockIdx.x;
    const int xcd = id & 7, seq = id >> 3;       // seq 0..63
    const int bh = xcd * 2 + (seq >> 5);
    const int inner = seq & 31;
    const int lt16 = inner >> 1;                 // 0..15
    const int js = inner & 1;                    // 0..1
    const int jbase = js * 8;
    const int b = bh >> 3, h = bh & 7;
    const int l0 = lt16 * 128;
    const int t = threadIdx.x;
    const int lane = t & 63, wid = t >> 6;
    const int wr = wid >> 1, wc = wid & 1;
    const int lrow = lane & 15, lk = lane >> 4;

    __shared__ __align__(16) f16 kbuf[2][2][128 * 64];  // [dbuf][hi/lo] 64 KB
    __shared__ float kbar_lds[64];
    __shared__ float dot_lds[128];
    __shared__ float wv_[4];
    __shared__ int wi_[4];

    // q fragments in registers (loaded once)
    f16x8 qa_h[2][4], qa_l[2][4];
    {
        const size_t qrowbase = (size_t)(b * L_ + l0 + wr * 64) * D_ + h * DK;
#pragma unroll
        for (int kk = 0; kk < 2; kk++)
#pragma unroll
            for (int lt = 0; lt < 4; lt++) {
                const size_t o = qrowbase + (size_t)(lt * 16 + lrow) * D_ + kk * 32 + lk * 8;
                qa_h[kk][lt] = *(const f16x8*)&qh[o];
                qa_l[kk][lt] = *(const f16x8*)&ql[o];
            }
    }
    if (t < 64) kbar_lds[t] = kbar[bh * 64 + t];

    const f16* khb = kh + (size_t)b * L_ * D_ + h * DK;
    const f16* klb = kl + (size_t)b * L_ * D_ + h * DK;

    const int srw = lane >> 3;
    const int scg = (lane & 7) ^ srw;
#define STAGE_TILE(jt, nb)                                                     \
    {                                                                          \
        const size_t gb0 = (size_t)((jt) * 128) * D_;                          \
        _Pragma("unroll")                                                      \
        for (int i_ = 0; i_ < 4; i_++) {                                       \
            const int chunk = wid * 4 + i_;                                    \
            const size_t go = gb0 + (size_t)(chunk * 8 + srw) * D_ + scg * 8;  \
            __builtin_amdgcn_global_load_lds(                                  \
                (const AS1 void*)(khb + go),                                   \
                (AS3 void*)(&kbuf[nb][0][chunk * 512]), 16, 0, 0);             \
            __builtin_amdgcn_global_load_lds(                                  \
                (const AS1 void*)(klb + go),                                   \
                (AS3 void*)(&kbuf[nb][1][chunk * 512]), 16, 0, 0);             \
        }                                                                      \
    }

    STAGE_TILE(jbase, 0)
    __syncthreads();

    float rmax[4][4];
#pragma unroll
    for (int lt = 0; lt < 4; lt++)
#pragma unroll
        for (int r = 0; r < 4; r++) rmax[lt][r] = -3.9e38f;

    int cur = 0;
    for (int jj = 0; jj < 8; jj++) {
        const int jt = jbase + jj;
        if (jj < 7) STAGE_TILE(jt + 1, cur ^ 1)

        f32x4 acc[4][4];
#pragma unroll
        for (int i = 0; i < 4; i++)
#pragma unroll
            for (int j = 0; j < 4; j++)
#pragma unroll
                for (int r = 0; r < 4; r++) acc[i][j][r] = 0.f;

#pragma unroll
        for (int kk = 0; kk < 2; kk++) {
            f16x8 bhf[4], blf[4];
#pragma unroll
            for (int jtt = 0; jtt < 4; jtt++) {
                const int row = wc * 64 + jtt * 16 + lrow;
                const int cs = (kk * 4 + lk) ^ (row & 7);
                const int o = row * 64 + cs * 8;
                bhf[jtt] = *(const f16x8*)&kbuf[cur][0][o];
                blf[jtt] = *(const f16x8*)&kbuf[cur][1][o];
            }
#pragma unroll
            for (int lt = 0; lt < 4; lt++)
#pragma unroll
                for (int jtt = 0; jtt < 4; jtt++) {
                    acc[lt][jtt] = __builtin_amdgcn_mfma_f32_16x16x32_f16(
                        qa_h[kk][lt], bhf[jtt], acc[lt][jtt], 0, 0, 0);
                    acc[lt][jtt] = __builtin_amdgcn_mfma_f32_16x16x32_f16(
                        qa_h[kk][lt], blf[jtt], acc[lt][jtt], 0, 0, 0);
                    acc[lt][jtt] = __builtin_amdgcn_mfma_f32_16x16x32_f16(
                        qa_l[kk][lt], bhf[jtt], acc[lt][jtt], 0, 0, 0);
                }
        }

#pragma unroll
        for (int jtt = 0; jtt < 4; jtt++) {
            const int cj = jt * 128 + wc * 64 + jtt * 16 + lrow;
            const float addend = (counts[cj] > 0) ? 0.f : -3.0e38f;
#pragma unroll
            for (int lt = 0; lt < 4; lt++)
#pragma unroll
                for (int r = 0; r < 4; r++)
                    rmax[lt][r] = fmaxf(rmax[lt][r], acc[lt][jtt][r] + addend);
        }

        __syncthreads();   // drains vmcnt -> staged tile ready
        cur ^= 1;
    }

    // reduce row-max across the 16 column-lanes
#pragma unroll
    for (int m = 1; m < 16; m <<= 1)
#pragma unroll
        for (int lt = 0; lt < 4; lt++)
#pragma unroll
            for (int r = 0; r < 4; r++)
                rmax[lt][r] = fmaxf(rmax[lt][r], __shfl_xor(rmax[lt][r], m));

    // q.kbar dot from registers
    {
        float dlt[4];
#pragma unroll
        for (int lt = 0; lt < 4; lt++) {
            float d = 0.f;
#pragma unroll
            for (int kk = 0; kk < 2; kk++) {
                const f16x8 hv = qa_h[kk][lt];
                const f16x8 lv = qa_l[kk][lt];
#pragma unroll
                for (int i = 0; i < 8; i++)
                    d += ((float)hv[i] + (float)lv[i]) * kbar_lds[kk * 32 + lk * 8 + i];
            }
            dlt[lt] = d;
        }
#pragma unroll
        for (int lt = 0; lt < 4; lt++) {
            dlt[lt] += __shfl_xor(dlt[lt], 16);
            dlt[lt] += __shfl_xor(dlt[lt], 32);
        }
        if (lane < 16) {
#pragma unroll
            for (int lt = 0; lt < 4; lt++)
                dot_lds[wr * 64 + lt * 16 + lane] = dlt[lt];
        }
    }
    __syncthreads();

    // block argmax of (rmax - dot)
    float bv_ = -3.9e38f;
    int bi_ = 0x7fffffff;
#pragma unroll
    for (int lt = 0; lt < 4; lt++)
#pragma unroll
        for (int r = 0; r < 4; r++) {
            const int rl_ = wr * 64 + lt * 16 + lk * 4 + r;
            const float val = rmax[lt][r] - dot_lds[rl_];
            const int idx = l0 + rl_;
            if (val > bv_ || (val == bv_ && idx < bi_)) { bv_ = val; bi_ = idx; }
        }
#pragma unroll
    for (int m = 1; m < 64; m <<= 1) {
        const float ov = __shfl_xor(bv_, m);
        const int oi = __shfl_xor(bi_, m);
        if (ov > bv_ || (ov == bv_ && oi < bi_)) { bv_ = ov; bi_ = oi; }
    }
    if (lane == 0) { wv_[wid] = bv_; wi_[wid] = bi_; }
    __syncthreads();
    if (t == 0) {
        float fb = wv_[0]; int fi = wi_[0];
#pragma unroll
        for (int w = 1; w < 4; w++) {
            if (wv_[w] > fb || (wv_[w] == fb && wi_[w] < fi)) { fb = wv_[w]; fi = wi_[w]; }
        }
        bestv[bh * 32 + lt16 * 2 + js] = fb;
        besti[bh * 32 + lt16 * 2 + js] = fi;
    }
#undef STAGE_TILE
}

// ---------------------------------------------------------------------------
// tail: ctx_part (blocks 0..255) -> gate -> ctx_combine (256..271) -> gate
// -> out (272..399).  Device-scope flag gates; all 400 blocks co-resident
// (tiny LDS/VGPR), so spinning consumers never starve producers.
// ---------------------------------------------------------------------------
__global__ __launch_bounds__(256) void tail_kernel(
    const f16* __restrict__ qh, const f16* __restrict__ ql,
    const f16* __restrict__ kh, const f16* __restrict__ kl,
    const float* __restrict__ x,
    const float* __restrict__ bestv, const int* __restrict__ besti,
    const float* __restrict__ Wv, const float* __restrict__ bv,
    const float* __restrict__ Wo, const float* __restrict__ bo,
    float* __restrict__ xbar_part, float* __restrict__ cm,
    float* __restrict__ cs, float* __restrict__ ctx,
    float* __restrict__ out, int* __restrict__ flags)
{
    const int bid = blockIdx.x;
    const int t = threadIdx.x;

    if (bid < 256) {
        // ================= ctx_part =================
        const int c = bid & 127;     // 16-row chunk
        const int b = bid >> 7;      // batch
        const int l0 = c * 16;

        __shared__ float qr[8][64];
        __shared__ float w[8][16];
        __shared__ int u_lds[8];

        if (t < 8) {
            const int bh = b * 8 + t;
            float best = -3.9e38f; int bi = 0x7fffffff;
            for (int cc = 0; cc < 32; cc++) {
                const float v = bestv[bh * 32 + cc];
                const int oi = besti[bh * 32 + cc];
                if (v > best || (v == best && oi < bi)) { best = v; bi = oi; }
            }
            u_lds[t] = bi;
        }
        __syncthreads();

        {
            const int h = t >> 5, i2 = (t & 31) * 2;
            const int u = u_lds[h];
            const size_t o = (size_t)(b * L_ + u) * D_ + h * DK + i2;
            qr[h][i2]     = (float)qh[o]     + (float)ql[o];
            qr[h][i2 + 1] = (float)qh[o + 1] + (float)ql[o + 1];
        }
        __syncthreads();

        {
            const int dotid = t >> 1, half = t & 1;
            const int row = dotid & 15, h = dotid >> 4;
            const size_t off = (size_t)(b * L_ + l0 + row) * D_ + h * DK + half * 32;
            const f16* krh = kh + off;
            const f16* krl = kl + off;
            float dot = 0.f;
#pragma unroll
            for (int cc = 0; cc < 4; cc++) {
                const f16x8 hv = *(const f16x8*)&krh[cc * 8];
                const f16x8 lv = *(const f16x8*)&krl[cc * 8];
#pragma unroll
                for (int i = 0; i < 8; i++)
                    dot += ((float)hv[i] + (float)lv[i]) * qr[h][half * 32 + cc * 8 + i];
            }
            dot += __shfl_xor(dot, 1);
            if (half == 0) w[h][row] = dot * SCALE;
        }
        __syncthreads();

        if (t < 8) {
            float m = w[t][0];
#pragma unroll
            for (int i = 1; i < 16; i++) m = fmaxf(m, w[t][i]);
            float s = 0.f;
#pragma unroll
            for (int i = 0; i < 16; i++) {
                const float e = expf(w[t][i] - m);
                w[t][i] = e;
                s += e;
            }
            cm[(size_t)(b * 8 + t) * 128 + c] = m;
            cs[(size_t)(b * 8 + t) * 128 + c] = s;
        }
        __syncthreads();

        {
            float ax[8], ay[8];
#pragma unroll
            for (int h = 0; h < 8; h++) { ax[h] = 0.f; ay[h] = 0.f; }
            const float* xb = x + (size_t)(b * L_ + l0) * D_ + t * 2;
#pragma unroll
            for (int i = 0; i < 16; i++) {
                const float2 xv = *(const float2*)(xb + (size_t)i * D_);
#pragma unroll
                for (int h = 0; h < 8; h++) {
                    ax[h] = fmaf(w[h][i], xv.x, ax[h]);
                    ay[h] = fmaf(w[h][i], xv.y, ay[h]);
                }
            }
#pragma unroll
            for (int h = 0; h < 8; h++) {
                float2 st; st.x = ax[h]; st.y = ay[h];
                *(float2*)&xbar_part[((size_t)(b * 8 + h) * 128 + c) * 512 + t * 2] = st;
            }
        }

        __threadfence();
        __syncthreads();
        if (t == 0)
            __hip_atomic_fetch_add(&flags[0], 1, __ATOMIC_RELEASE,
                                   __HIP_MEMORY_SCOPE_AGENT);
    } else if (bid < 272) {
        // ================= ctx_combine =================
        const int bh = bid - 256;
        const int h = bh & 7;
        __shared__ float xbar[512];

        if (t == 0) {
            while (__hip_atomic_load(&flags[0], __ATOMIC_ACQUIRE,
                                     __HIP_MEMORY_SCOPE_AGENT) < 256)
                __builtin_amdgcn_s_sleep(8);
        }
        __syncthreads();

        float M = -3.9e38f;
        for (int cc = 0; cc < 128; cc++) M = fmaxf(M, cm[(size_t)bh * 128 + cc]);
        float denom = 0.f, ax = 0.f, ay = 0.f;
        for (int cc = 0; cc < 128; cc++) {
            const float f = expf(cm[(size_t)bh * 128 + cc] - M);
            denom += f * cs[(size_t)bh * 128 + cc];
            const float2 p = *(const float2*)
                &xbar_part[((size_t)bh * 128 + cc) * 512 + t * 2];
            ax = fmaf(f, p.x, ax);
            ay = fmaf(f, p.y, ay);
        }
        xbar[t * 2] = ax; xbar[t * 2 + 1] = ay;
        __syncthreads();

        if (t < 64) {
            const float* wr = Wv + (size_t)(h * 64 + t) * D_;
            float acc = 0.f;
#pragma unroll 8
            for (int d = 0; d < 128; d++) {
                const float4 wv4 = *(const float4*)&wr[d * 4];
                acc += wv4.x * xbar[d * 4] + wv4.y * xbar[d * 4 + 1] +
                       wv4.z * xbar[d * 4 + 2] + wv4.w * xbar[d * 4 + 3];
            }
            ctx[bh * 64 + t] = acc / denom + bv[h * 64 + t];
        }

        __threadfence();
        __syncthreads();
        if (t == 0)
            __hip_atomic_fetch_add(&flags[1], 1, __ATOMIC_RELEASE,
                                   __HIP_MEMORY_SCOPE_AGENT);
    } else {
        // ================= out =================
        const int idx = bid - 272;   // 0..127
        const int b = idx >> 6;      // 0..1
        const int sl = idx & 63;     // 0..63 (32-row slices)
        __shared__ float cb[512];
        __shared__ float row[512];

        if (t == 0) {
            while (__hip_atomic_load(&flags[1], __ATOMIC_ACQUIRE,
                                     __HIP_MEMORY_SCOPE_AGENT) < 16)
                __builtin_amdgcn_s_sleep(8);
        }
        __syncthreads();

        cb[t] = ctx[b * 512 + t];
        cb[t + 256] = ctx[b * 512 + 256 + t];
        __syncthreads();

#pragma unroll
        for (int r = 0; r < 2; r++) {
            const int e = t + r * 256;
            const float* wr = Wo + (size_t)e * D_;
            float acc = 0.f;
#pragma unroll 8
            for (int c = 0; c < 128; c++) {
                const float4 wv = *(const float4*)(wr + c * 4);
                acc += wv.x * cb[c * 4] + wv.y * cb[c * 4 + 1] +
                       wv.z * cb[c * 4 + 2] + wv.w * cb[c * 4 + 3];
            }
            row[e] = acc + bo[e];
        }
        __syncthreads();

        const float4* r4 = (const float4*)row;
        float4* o4 = (float4*)(out + ((size_t)b * L_ + sl * 32) * D_);
        for (int i = t; i < 32 * 128; i += 256) {
            const int l = i >> 7, c = i & 127;
            o4[l * 128 + c] = r4[c];
        }
    }
}

// ---------------------------------------------------------------------------
extern "C" void kernel_launch(void* const* d_in, const int* in_sizes, int n_in,
                              void* d_out, int out_size, void* d_ws, size_t ws_size,
                              hipStream_t stream)
{
    const float* x   = (const float*)d_in[0];
    const int* samp  = (const int*)d_in[1];
    const float* Wq  = (const float*)d_in[2];
    const float* bq  = (const float*)d_in[3];
    const float* Wk  = (const float*)d_in[4];
    const float* bk  = (const float*)d_in[5];
    const float* Wv  = (const float*)d_in[6];
    const float* bv  = (const float*)d_in[7];
    const float* Wo  = (const float*)d_in[8];
    const float* bo  = (const float*)d_in[9];
    float* out = (float*)d_out;

    f16* qh = (f16*)d_ws;
    f16* ql = qh + QSZ;
    f16* kh = ql + QSZ;
    f16* kl = kh + QSZ;
    f16* xh = kl + QSZ;
    f16* xl = xh + QSZ;
    f16* wh = xl + QSZ;                       // 1024*512
    f16* wl = wh + 1024 * 512;
    float* fbase     = (float*)(wl + 1024 * 512);
    float* biascat   = fbase;                 // 1024
    float* xbc_part  = biascat + 1024;        // 2*32*512 = 32768
    float* xbar_part = xbc_part + 32768;      // 16*128*512 = 1048576
    float* cm        = xbar_part + 1048576;   // 2048
    float* cs        = cm + 2048;             // 2048
    float* bestv     = cs + 2048;             // 512
    float* kbar      = bestv + 512;           // 1024
    float* ctx       = kbar + 1024;           // 1024
    int* counts      = (int*)(ctx + 1024);    // 2048
    int* besti       = counts + 2048;         // 512
    int* flags       = besti + 512;           // 2

    prep_kernel<<<1346, 256, 0, stream>>>(x, Wq, Wk, bq, bk, samp,
                                          xh, xl, wh, wl, biascat, counts,
                                          xbc_part, flags);
    projqk_kernel<<<272, 256, 0, stream>>>(xh, xl, wh, wl, biascat,
                                           xbc_part, Wk, bk, samp, counts, kbar,
                                           qh, ql, kh, kl);
    mstat_kernel<<<512, 256, 0, stream>>>(qh, ql, kh, kl, counts, kbar,
                                          bestv, besti);
    tail_kernel<<<400, 256, 0, stream>>>(qh, ql, kh, kl, x, bestv, besti,
                                         Wv, bv, Wo, bo,
                                         xbar_part, cm, cs, ctx, out, flags);
}

// Round 13
// 142.997 us; speedup vs baseline: 1.7133x; 1.7133x over previous
//
#include <hip/hip_runtime.h>

#define B_ 2
#define L_ 2048
#define D_ 512
#define H_ 8
#define DK 64
#define S_ 10240
#define SCALE 0.125f

#define QSZ (4096 * 512)  // B_*L_*D_ elements

typedef _Float16 f16;
typedef __attribute__((ext_vector_type(8))) _Float16 f16x8;
typedef __attribute__((ext_vector_type(4))) float f32x4;

#define AS1 __attribute__((address_space(1)))
#define AS3 __attribute__((address_space(3)))

// ---------------------------------------------------------------------------
// prep: split x -> xh/xl, split Wq|Wk -> wh/wl + biascat, xbar_c partials,
// and zero the counts histogram (hist itself runs inside projqk, after).
// ---------------------------------------------------------------------------
__global__ __launch_bounds__(256) void prep_kernel(
    const float* __restrict__ x,
    const float* __restrict__ Wq, const float* __restrict__ Wk,
    const float* __restrict__ bq, const float* __restrict__ bk,
    const int* __restrict__ samp,
    f16* __restrict__ xh, f16* __restrict__ xl,
    f16* __restrict__ wh, f16* __restrict__ wl,
    float* __restrict__ biascat, int* __restrict__ counts,
    float* __restrict__ xbc_part)
{
    const int bid = blockIdx.x;
    const int t = threadIdx.x;
    if (bid < 1024) {
        const size_t i0 = ((size_t)bid * 256 + t) * 8;
        const float4 a = *(const float4*)&x[i0];
        const float4 b = *(const float4*)&x[i0 + 4];
        const float vals[8] = {a.x, a.y, a.z, a.w, b.x, b.y, b.z, b.w};
        union { f16 h[8]; uint4 u; } H, Lo;
#pragma unroll
        for (int j = 0; j < 8; j++) {
            const f16 hh = (f16)vals[j];
            H.h[j] = hh;
            Lo.h[j] = (f16)(vals[j] - (float)hh);
        }
        *(uint4*)&xh[i0] = H.u;
        *(uint4*)&xl[i0] = Lo.u;
    } else if (bid < 1280) {
        const size_t i0 = ((size_t)(bid - 1024) * 256 + t) * 8;
        const float* src = (i0 < (size_t)512 * 512) ? Wq + i0
                                                    : Wk + (i0 - (size_t)512 * 512);
        const float4 a = *(const float4*)&src[0];
        const float4 b = *(const float4*)&src[4];
        const float vals[8] = {a.x, a.y, a.z, a.w, b.x, b.y, b.z, b.w};
        union { f16 h[8]; uint4 u; } H, Lo;
#pragma unroll
        for (int j = 0; j < 8; j++) {
            const f16 hh = (f16)vals[j];
            H.h[j] = hh;
            Lo.h[j] = (f16)(vals[j] - (float)hh);
        }
        *(uint4*)&wh[i0] = H.u;
        *(uint4*)&wl[i0] = Lo.u;
        if (bid == 1024)
            for (int e = t; e < 1024; e += 256)
                biascat[e] = (e < 512) ? bq[e] : bk[e - 512];
    } else if (bid < 1344) {
        // xbar_c partials: sum of x rows over a 320-sample slice
        const int p = bid - 1280;            // 0..63
        const int bb = p >> 5, chunk = p & 31;
        const int s0 = chunk * 320;
        float ax = 0.f, ay = 0.f;
        const float* xb = x + (size_t)bb * L_ * D_ + t * 2;
        for (int i = 0; i < 320; i++) {
            const int j = samp[s0 + i];
            const float2 v = *(const float2*)(xb + (size_t)j * D_);
            ax += v.x; ay += v.y;
        }
        float2 st; st.x = ax; st.y = ay;
        *(float2*)&xbc_part[((size_t)(bb * 32 + chunk)) * 512 + t * 2] = st;
    } else {
        // zero counts: 2 blocks x 256 threads x int4 = 2048 ints
        int4 z; z.x = 0; z.y = 0; z.z = 0; z.w = 0;
        ((int4*)counts)[(bid - 1344) * 256 + t] = z;
    }
}

// ---------------------------------------------------------------------------
// q,k projections via split-f16 MFMA GEMM: [4096 x 512] . [512 x 1024]^T
// 64x128 tiles (512 blocks, 48 KB LDS -> 2-3 blocks/CU for latency overlap).
// Staging via global_load_lds with pre-swizzled source.
// Blocks 512..527 (tail-scheduled): kbar = xbar_c . Wk_h + bk_h, + histogram.
// ---------------------------------------------------------------------------
__global__ __launch_bounds__(256) void projqk_kernel(
    const f16* __restrict__ xh, const f16* __restrict__ xl,
    const f16* __restrict__ wh, const f16* __restrict__ wl,
    const float* __restrict__ biascat,
    const float* __restrict__ xbc_part, const float* __restrict__ Wk,
    const float* __restrict__ bk, const int* __restrict__ samp,
    int* __restrict__ counts, float* __restrict__ kbar,
    f16* __restrict__ qh, f16* __restrict__ ql,
    f16* __restrict__ kh, f16* __restrict__ kl)
{
    const int bid = blockIdx.x;
    const int t = threadIdx.x;

    __shared__ __align__(16) f16 lds[24576];   // 48 KB

    if (bid >= 512) {
        // ---- kbar + histogram block (runs in the tail on freed CUs) ----
        const int bh = bid - 512;
        const int b = bh >> 3, h = bh & 7;
        float* xc = (float*)lds;

        for (int i = bh * 640 + t; i < (bh + 1) * 640; i += 256)
            atomicAdd(&counts[samp[i]], 1);

        float ax = 0.f, ay = 0.f;
#pragma unroll
        for (int p = 0; p < 32; p++) {
            const float2 v = *(const float2*)&xbc_part[((size_t)(b * 32 + p)) * 512 + t * 2];
            ax += v.x; ay += v.y;
        }
        xc[t * 2]     = ax * (1.0f / (float)S_);
        xc[t * 2 + 1] = ay * (1.0f / (float)S_);
        __syncthreads();

        const int row = t >> 2, quarter = t & 3;
        const float* wr = Wk + (size_t)(h * 64 + row) * 512 + quarter * 128;
        float s = 0.f;
#pragma unroll 8
        for (int d = 0; d < 32; d++) {
            const float4 w4 = *(const float4*)&wr[d * 4];
            const int xo = quarter * 128 + d * 4;
            s += w4.x * xc[xo] + w4.y * xc[xo + 1] + w4.z * xc[xo + 2] + w4.w * xc[xo + 3];
        }
        s += __shfl_xor(s, 1);
        s += __shfl_xor(s, 2);
        if (quarter == 0) kbar[bh * 64 + row] = s + bk[h * 64 + row];
        return;
    }

    // ---- GEMM block: 64 rows x 128 cols ----
    const int n0 = (bid & 63) * 64;    // rows (tokens)
    const int e0 = (bid >> 6) * 128;   // cols (proj dims, 0..1023)

    f16* ash = lds;            // 64 x 64
    f16* asl = lds + 4096;
    f16* bsh = lds + 8192;     // 128 x 64
    f16* bsl = lds + 16384;

    const int lane = t & 63, wid = t >> 6;
    const int wr = wid >> 1, wc = wid & 1;
    const int lrow = lane & 15, lk = lane >> 4;
    const int srw = lane >> 3;               // row within 8-row group
    const int scg = (lane & 7) ^ srw;        // pre-swizzled global col chunk

    f32x4 acc[2][4];
#pragma unroll
    for (int i = 0; i < 2; i++)
#pragma unroll
        for (int j = 0; j < 4; j++)
#pragma unroll
            for (int r = 0; r < 4; r++) acc[i][j][r] = 0.f;

    for (int kt = 0; kt < 8; kt++) {
        __syncthreads();
        // A: 8 chunks of 8 rows, 2 per wave
#pragma unroll
        for (int i_ = 0; i_ < 2; i_++) {
            const int chunk = wid * 2 + i_;
            const int row = chunk * 8 + srw;
            const size_t goa = (size_t)(n0 + row) * 512 + kt * 64 + scg * 8;
            __builtin_amdgcn_global_load_lds((const AS1 void*)(xh + goa),
                                             (AS3 void*)(&ash[chunk * 512]), 16, 0, 0);
            __builtin_amdgcn_global_load_lds((const AS1 void*)(xl + goa),
                                             (AS3 void*)(&asl[chunk * 512]), 16, 0, 0);
        }
        // B: 16 chunks of 8 rows, 4 per wave
#pragma unroll
        for (int i_ = 0; i_ < 4; i_++) {
            const int chunk = wid * 4 + i_;
            const int row = chunk * 8 + srw;
            const size_t gob = (size_t)(e0 + row) * 512 + kt * 64 + scg * 8;
            __builtin_amdgcn_global_load_lds((const AS1 void*)(wh + gob),
                                             (AS3 void*)(&bsh[chunk * 512]), 16, 0, 0);
            __builtin_amdgcn_global_load_lds((const AS1 void*)(wl + gob),
                                             (AS3 void*)(&bsl[chunk * 512]), 16, 0, 0);
        }
        __syncthreads();

#pragma unroll
        for (int kk = 0; kk < 2; kk++) {
            f16x8 ah[2], al[2], bh_[4], bl_[4];
#pragma unroll
            for (int lt = 0; lt < 2; lt++) {
                const int row = wr * 32 + lt * 16 + lrow;
                const int cs = (kk * 4 + lk) ^ (row & 7);
                const int o = row * 64 + cs * 8;
                ah[lt] = *(const f16x8*)&ash[o];
                al[lt] = *(const f16x8*)&asl[o];
            }
#pragma unroll
            for (int jt = 0; jt < 4; jt++) {
                const int row = wc * 64 + jt * 16 + lrow;
                const int cs = (kk * 4 + lk) ^ (row & 7);
                const int o = row * 64 + cs * 8;
                bh_[jt] = *(const f16x8*)&bsh[o];
                bl_[jt] = *(const f16x8*)&bsl[o];
            }
#pragma unroll
            for (int lt = 0; lt < 2; lt++)
#pragma unroll
                for (int jt = 0; jt < 4; jt++) {
                    acc[lt][jt] = __builtin_amdgcn_mfma_f32_16x16x32_f16(
                        ah[lt], bh_[jt], acc[lt][jt], 0, 0, 0);
                    acc[lt][jt] = __builtin_amdgcn_mfma_f32_16x16x32_f16(
                        ah[lt], bl_[jt], acc[lt][jt], 0, 0, 0);
                    acc[lt][jt] = __builtin_amdgcn_mfma_f32_16x16x32_f16(
                        al[lt], bh_[jt], acc[lt][jt], 0, 0, 0);
                }
        }
    }

    // Epilogue: bias add, split to hi/lo, LDS transpose for coalesced stores.
    const int PSTR = 72;
    f16* tile = lds + wid * 32 * PSTR;   // 4 waves x 32 rows x 72
    const int ebase = e0 + wc * 64;
    const bool isQ = ((bid >> 6) < 4);
    const int colbase = ((bid >> 6) & 3) * 128;

#pragma unroll
    for (int round = 0; round < 2; round++) {
        __syncthreads();
#pragma unroll
        for (int jt = 0; jt < 4; jt++) {
            const float bval = biascat[ebase + jt * 16 + lrow];
#pragma unroll
            for (int lt = 0; lt < 2; lt++)
#pragma unroll
                for (int r = 0; r < 4; r++) {
                    const float y = acc[lt][jt][r] + bval;
                    const f16 hi = (f16)y;
                    const f16 val = (round == 0) ? hi : (f16)(y - (float)hi);
                    tile[(lt * 16 + lk * 4 + r) * PSTR + jt * 16 + lrow] = val;
                }
        }
        __syncthreads();
        f16* dst = isQ ? ((round == 0) ? qh : ql) : ((round == 0) ? kh : kl);
        // 64 rows x 16 col-chunks (8 f16 each) = 1024 uint4 stores
        for (int i = t; i < 1024; i += 256) {
            const int row = i >> 4, cc = i & 15;
            const int swid = (row >> 5) * 2 + (cc >> 3);
            const int trow = row & 31, tcol = (cc & 7) * 8;
            const int n = n0 + row;
            const int col = colbase + cc * 8;
            *(uint4*)&dst[(size_t)n * 512 + col] =
                *(const uint4*)&lds[swid * 32 * PSTR + trow * PSTR + tcol];
        }
    }
}

// ---------------------------------------------------------------------------
// mstat: per (l-chunk128, bh, j-half) block. q frags in registers, K staged
// HBM->LDS via global_load_lds, double-buffered.  Fused block argmax.
// ---------------------------------------------------------------------------
__global__ __launch_bounds__(256, 2) void mstat_kernel(
    const f16* __restrict__ qh, const f16* __restrict__ ql,
    const f16* __restrict__ kh, const f16* __restrict__ kl,
    const int* __restrict__ counts, const float* __restrict__ kbar,
    float* __restrict__ bestv, int* __restrict__ besti)
{
    const int id = blockIdx.x;
    const int xcd = id & 7, seq = id >> 3;       // seq 0..63
    const int bh = xcd * 2 + (seq >> 5);
    const int inner = seq & 31;
    const int lt16 = inner >> 1;                 // 0..15
    const int js = inner & 1;                    // 0..1
    const int jbase = js * 8;
    const int b = bh >> 3, h = bh & 7;
    const int l0 = lt16 * 128;
    const int t = threadIdx.x;
    const int lane = t & 63, wid = t >> 6;
    const int wr = wid >> 1, wc = wid & 1;
    const int lrow = lane & 15, lk = lane >> 4;

    __shared__ __align__(16) f16 kbuf[2][2][128 * 64];  // [dbuf][hi/lo] 64 KB
    __shared__ float kbar_lds[64];
    __shared__ float dot_lds[128];
    __shared__ float wv_[4];
    __shared__ int wi_[4];

    // q fragments in registers (loaded once)
    f16x8 qa_h[2][4], qa_l[2][4];
    {
        const size_t qrowbase = (size_t)(b * L_ + l0 + wr * 64) * D_ + h * DK;
#pragma unroll
        for (int kk = 0; kk < 2; kk++)
#pragma unroll
            for (int lt = 0; lt < 4; lt++) {
                const size_t o = qrowbase + (size_t)(lt * 16 + lrow) * D_ + kk * 32 + lk * 8;
                qa_h[kk][lt] = *(const f16x8*)&qh[o];
                qa_l[kk][lt] = *(const f16x8*)&ql[o];
            }
    }
    if (t < 64) kbar_lds[t] = kbar[bh * 64 + t];

    const f16* khb = kh + (size_t)b * L_ * D_ + h * DK;
    const f16* klb = kl + (size_t)b * L_ * D_ + h * DK;

    const int srw = lane >> 3;
    const int scg = (lane & 7) ^ srw;
#define STAGE_TILE(jt, nb)                                                     \
    {                                                                          \
        const size_t gb0 = (size_t)((jt) * 128) * D_;                          \
        _Pragma("unroll")                                                      \
        for (int i_ = 0; i_ < 4; i_++) {                                       \
            const int chunk = wid * 4 + i_;                                    \
            const size_t go = gb0 + (size_t)(chunk * 8 + srw) * D_ + scg * 8;  \
            __builtin_amdgcn_global_load_lds(                                  \
                (const AS1 void*)(khb + go),                                   \
                (AS3 void*)(&kbuf[nb][0][chunk * 512]), 16, 0, 0);             \
            __builtin_amdgcn_global_load_lds(                                  \
                (const AS1 void*)(klb + go),                                   \
                (AS3 void*)(&kbuf[nb][1][chunk * 512]), 16, 0, 0);             \
        }                                                                      \
    }

    STAGE_TILE(jbase, 0)
    __syncthreads();

    float rmax[4][4];
#pragma unroll
    for (int lt = 0; lt < 4; lt++)
#pragma unroll
        for (int r = 0; r < 4; r++) rmax[lt][r] = -3.9e38f;

    int cur = 0;
    for (int jj = 0; jj < 8; jj++) {
        const int jt = jbase + jj;
        if (jj < 7) STAGE_TILE(jt + 1, cur ^ 1)

        f32x4 acc[4][4];
#pragma unroll
        for (int i = 0; i < 4; i++)
#pragma unroll
            for (int j = 0; j < 4; j++)
#pragma unroll
                for (int r = 0; r < 4; r++) acc[i][j][r] = 0.f;

#pragma unroll
        for (int kk = 0; kk < 2; kk++) {
            f16x8 bhf[4], blf[4];
#pragma unroll
            for (int jtt = 0; jtt < 4; jtt++) {
                const int row = wc * 64 + jtt * 16 + lrow;
                const int cs = (kk * 4 + lk) ^ (row & 7);
                const int o = row * 64 + cs * 8;
                bhf[jtt] = *(const f16x8*)&kbuf[cur][0][o];
                blf[jtt] = *(const f16x8*)&kbuf[cur][1][o];
            }
#pragma unroll
            for (int lt = 0; lt < 4; lt++)
#pragma unroll
                for (int jtt = 0; jtt < 4; jtt++) {
                    acc[lt][jtt] = __builtin_amdgcn_mfma_f32_16x16x32_f16(
                        qa_h[kk][lt], bhf[jtt], acc[lt][jtt], 0, 0, 0);
                    acc[lt][jtt] = __builtin_amdgcn_mfma_f32_16x16x32_f16(
                        qa_h[kk][lt], blf[jtt], acc[lt][jtt], 0, 0, 0);
                    acc[lt][jtt] = __builtin_amdgcn_mfma_f32_16x16x32_f16(
                        qa_l[kk][lt], bhf[jtt], acc[lt][jtt], 0, 0, 0);
                }
        }

#pragma unroll
        for (int jtt = 0; jtt < 4; jtt++) {
            const int cj = jt * 128 + wc * 64 + jtt * 16 + lrow;
            const float addend = (counts[cj] > 0) ? 0.f : -3.0e38f;
#pragma unroll
            for (int lt = 0; lt < 4; lt++)
#pragma unroll
                for (int r = 0; r < 4; r++)
                    rmax[lt][r] = fmaxf(rmax[lt][r], acc[lt][jtt][r] + addend);
        }

        __syncthreads();   // drains vmcnt -> staged tile ready
        cur ^= 1;
    }

    // reduce row-max across the 16 column-lanes
#pragma unroll
    for (int m = 1; m < 16; m <<= 1)
#pragma unroll
        for (int lt = 0; lt < 4; lt++)
#pragma unroll
            for (int r = 0; r < 4; r++)
                rmax[lt][r] = fmaxf(rmax[lt][r], __shfl_xor(rmax[lt][r], m));

    // q.kbar dot from registers
    {
        float dlt[4];
#pragma unroll
        for (int lt = 0; lt < 4; lt++) {
            float d = 0.f;
#pragma unroll
            for (int kk = 0; kk < 2; kk++) {
                const f16x8 hv = qa_h[kk][lt];
                const f16x8 lv = qa_l[kk][lt];
#pragma unroll
                for (int i = 0; i < 8; i++)
                    d += ((float)hv[i] + (float)lv[i]) * kbar_lds[kk * 32 + lk * 8 + i];
            }
            dlt[lt] = d;
        }
#pragma unroll
        for (int lt = 0; lt < 4; lt++) {
            dlt[lt] += __shfl_xor(dlt[lt], 16);
            dlt[lt] += __shfl_xor(dlt[lt], 32);
        }
        if (lane < 16) {
#pragma unroll
            for (int lt = 0; lt < 4; lt++)
                dot_lds[wr * 64 + lt * 16 + lane] = dlt[lt];
        }
    }
    __syncthreads();

    // block argmax of (rmax - dot)
    float bv_ = -3.9e38f;
    int bi_ = 0x7fffffff;
#pragma unroll
    for (int lt = 0; lt < 4; lt++)
#pragma unroll
        for (int r = 0; r < 4; r++) {
            const int rl_ = wr * 64 + lt * 16 + lk * 4 + r;
            const float val = rmax[lt][r] - dot_lds[rl_];
            const int idx = l0 + rl_;
            if (val > bv_ || (val == bv_ && idx < bi_)) { bv_ = val; bi_ = idx; }
        }
#pragma unroll
    for (int m = 1; m < 64; m <<= 1) {
        const float ov = __shfl_xor(bv_, m);
        const int oi = __shfl_xor(bi_, m);
        if (ov > bv_ || (ov == bv_ && oi < bi_)) { bv_ = ov; bi_ = oi; }
    }
    if (lane == 0) { wv_[wid] = bv_; wi_[wid] = bi_; }
    __syncthreads();
    if (t == 0) {
        float fb = wv_[0]; int fi = wi_[0];
#pragma unroll
        for (int w = 1; w < 4; w++) {
            if (wv_[w] > fb || (wv_[w] == fb && wi_[w] < fi)) { fb = wv_[w]; fi = wi_[w]; }
        }
        bestv[bh * 32 + lt16 * 2 + js] = fb;
        besti[bh * 32 + lt16 * 2 + js] = fi;
    }
#undef STAGE_TILE
}

// ---------------------------------------------------------------------------
// ctx stage 1: block per (16-row chunk, b).  Fused final argmax; computes
// scores for all 8 heads, per-head softmax partials, and x-weighted partial
// (context = (sum_l attn_l x_l) . Wv + bv  since sum attn = 1).
// ---------------------------------------------------------------------------
__global__ __launch_bounds__(256) void ctx_part_kernel(
    const f16* __restrict__ qh, const f16* __restrict__ ql,
    const f16* __restrict__ kh, const f16* __restrict__ kl,
    const float* __restrict__ x,
    const float* __restrict__ bestv, const int* __restrict__ besti,
    float* __restrict__ xbar_part, float* __restrict__ cm, float* __restrict__ cs)
{
    const int c = blockIdx.x;     // 0..127 (16-row chunk)
    const int b = blockIdx.y;     // 0..1
    const int l0 = c * 16;
    const int t = threadIdx.x;

    __shared__ float qr[8][64];
    __shared__ float w[8][16];
    __shared__ int u_lds[8];

    // fused argmax over the 32 mstat chunks (ascending; min-idx tie-break)
    if (t < 8) {
        const int bh = b * 8 + t;
        float best = -3.9e38f; int bi = 0x7fffffff;
        for (int cc = 0; cc < 32; cc++) {
            const float v = bestv[bh * 32 + cc];
            const int oi = besti[bh * 32 + cc];
            if (v > best || (v == best && oi < bi)) { best = v; bi = oi; }
        }
        u_lds[t] = bi;
    }
    __syncthreads();

    // load q_u for all 8 heads
    {
        const int h = t >> 5, i2 = (t & 31) * 2;
        const int u = u_lds[h];
        const size_t o = (size_t)(b * L_ + u) * D_ + h * DK + i2;
        qr[h][i2]     = (float)qh[o]     + (float)ql[o];
        qr[h][i2 + 1] = (float)qh[o + 1] + (float)ql[o + 1];
    }
    __syncthreads();

    // scores: 128 dots (16 rows x 8 heads), 2 threads per dot
    {
        const int dotid = t >> 1, half = t & 1;
        const int row = dotid & 15, h = dotid >> 4;
        const size_t off = (size_t)(b * L_ + l0 + row) * D_ + h * DK + half * 32;
        const f16* krh = kh + off;
        const f16* krl = kl + off;
        float dot = 0.f;
#pragma unroll
        for (int cc = 0; cc < 4; cc++) {
            const f16x8 hv = *(const f16x8*)&krh[cc * 8];
            const f16x8 lv = *(const f16x8*)&krl[cc * 8];
#pragma unroll
            for (int i = 0; i < 8; i++)
                dot += ((float)hv[i] + (float)lv[i]) * qr[h][half * 32 + cc * 8 + i];
        }
        dot += __shfl_xor(dot, 1);
        if (half == 0) w[h][row] = dot * SCALE;
    }
    __syncthreads();

    // per-head chunk max + expsum
    if (t < 8) {
        float m = w[t][0];
#pragma unroll
        for (int i = 1; i < 16; i++) m = fmaxf(m, w[t][i]);
        float s = 0.f;
#pragma unroll
        for (int i = 0; i < 16; i++) {
            const float e = expf(w[t][i] - m);
            w[t][i] = e;
            s += e;
        }
        cm[(size_t)(b * 8 + t) * 128 + c] = m;
        cs[(size_t)(b * 8 + t) * 128 + c] = s;
    }
    __syncthreads();

    // x-weighted partials for all 8 heads; thread owns cols 2t, 2t+1
    {
        float ax[8], ay[8];
#pragma unroll
        for (int h = 0; h < 8; h++) { ax[h] = 0.f; ay[h] = 0.f; }
        const float* xb = x + (size_t)(b * L_ + l0) * D_ + t * 2;
#pragma unroll
        for (int i = 0; i < 16; i++) {
            const float2 xv = *(const float2*)(xb + (size_t)i * D_);
#pragma unroll
            for (int h = 0; h < 8; h++) {
                ax[h] = fmaf(w[h][i], xv.x, ax[h]);
                ay[h] = fmaf(w[h][i], xv.y, ay[h]);
            }
        }
#pragma unroll
        for (int h = 0; h < 8; h++) {
            float2 st; st.x = ax[h]; st.y = ay[h];
            *(float2*)&xbar_part[((size_t)(b * 8 + h) * 128 + c) * 512 + t * 2] = st;
        }
    }
}

// ---------------------------------------------------------------------------
// combine 128 chunk partials -> xbar, then ctx slice = xbar . Wv_h + bv_h
// ---------------------------------------------------------------------------
__global__ __launch_bounds__(256) void ctx_combine_kernel(
    const float* __restrict__ xbar_part, const float* __restrict__ cm,
    const float* __restrict__ cs, const float* __restrict__ Wv,
    const float* __restrict__ bv, float* __restrict__ ctx)
{
    const int bh = blockIdx.x;
    const int h = bh & 7;
    const int t = threadIdx.x;
    __shared__ float xbar[512];

    float M = -3.9e38f;
    for (int cc = 0; cc < 128; cc++) M = fmaxf(M, cm[(size_t)bh * 128 + cc]);
    float denom = 0.f, ax = 0.f, ay = 0.f;
    for (int cc = 0; cc < 128; cc++) {
        const float f = expf(cm[(size_t)bh * 128 + cc] - M);
        denom += f * cs[(size_t)bh * 128 + cc];
        const float2 p = *(const float2*)
            &xbar_part[((size_t)bh * 128 + cc) * 512 + t * 2];
        ax = fmaf(f, p.x, ax);
        ay = fmaf(f, p.y, ay);
    }
    xbar[t * 2] = ax; xbar[t * 2 + 1] = ay;
    __syncthreads();

    if (t < 64) {
        const float* wr = Wv + (size_t)(h * 64 + t) * D_;
        float acc = 0.f;
#pragma unroll 8
        for (int d = 0; d < 128; d++) {
            const float4 wv4 = *(const float4*)&wr[d * 4];
            acc += wv4.x * xbar[d * 4] + wv4.y * xbar[d * 4 + 1] +
                   wv4.z * xbar[d * 4 + 2] + wv4.w * xbar[d * 4 + 3];
        }
        ctx[bh * 64 + t] = acc / denom + bv[h * 64 + t];
    }
}

// ---------------------------------------------------------------------------
// out: each block recomputes the 512-row (Wo is L2-hot) and writes a
// 32-row slice.  out[b,l,e] = ctx[b] . Wo[e,:] + bo[e], broadcast over l.
// ---------------------------------------------------------------------------
__global__ __launch_bounds__(256) void out_kernel(
    const float* __restrict__ ctx, const float* __restrict__ Wo,
    const float* __restrict__ bo, float* __restrict__ out)
{
    const int b = blockIdx.x;    // 0..1
    const int sl = blockIdx.y;   // 0..63 (32-row slices)
    const int t = threadIdx.x;
    __shared__ float cb[512];
    __shared__ float row[512];

    cb[t] = ctx[b * 512 + t];
    cb[t + 256] = ctx[b * 512 + 256 + t];
    __syncthreads();

#pragma unroll
    for (int r = 0; r < 2; r++) {
        const int e = t + r * 256;
        const float* wr = Wo + (size_t)e * D_;
        float acc = 0.f;
#pragma unroll 8
        for (int c = 0; c < 128; c++) {
            const float4 wv = *(const float4*)(wr + c * 4);
            acc += wv.x * cb[c * 4] + wv.y * cb[c * 4 + 1] +
                   wv.z * cb[c * 4 + 2] + wv.w * cb[c * 4 + 3];
        }
        row[e] = acc + bo[e];
    }
    __syncthreads();

    const float4* r4 = (const float4*)row;
    float4* o4 = (float4*)(out + ((size_t)b * L_ + sl * 32) * D_);
    for (int i = t; i < 32 * 128; i += 256) {
        const int l = i >> 7, c = i & 127;
        o4[l * 128 + c] = r4[c];
    }
}

// ---------------------------------------------------------------------------
extern "C" void kernel_launch(void* const* d_in, const int* in_sizes, int n_in,
                              void* d_out, int out_size, void* d_ws, size_t ws_size,
                              hipStream_t stream)
{
    const float* x   = (const float*)d_in[0];
    const int* samp  = (const int*)d_in[1];
    const float* Wq  = (const float*)d_in[2];
    const float* bq  = (const float*)d_in[3];
    const float* Wk  = (const float*)d_in[4];
    const float* bk  = (const float*)d_in[5];
    const float* Wv  = (const float*)d_in[6];
    const float* bv  = (const float*)d_in[7];
    const float* Wo  = (const float*)d_in[8];
    const float* bo  = (const float*)d_in[9];
    float* out = (float*)d_out;

    f16* qh = (f16*)d_ws;
    f16* ql = qh + QSZ;
    f16* kh = ql + QSZ;
    f16* kl = kh + QSZ;
    f16* xh = kl + QSZ;
    f16* xl = xh + QSZ;
    f16* wh = xl + QSZ;                       // 1024*512
    f16* wl = wh + 1024 * 512;
    float* fbase     = (float*)(wl + 1024 * 512);
    float* biascat   = fbase;                 // 1024
    float* xbc_part  = biascat + 1024;        // 2*32*512 = 32768
    float* xbar_part = xbc_part + 32768;      // 16*128*512 = 1048576
    float* cm        = xbar_part + 1048576;   // 2048
    float* cs        = cm + 2048;             // 2048
    float* bestv     = cs + 2048;             // 512
    float* kbar      = bestv + 512;           // 1024
    float* ctx       = kbar + 1024;           // 1024
    int* counts      = (int*)(ctx + 1024);    // 2048
    int* besti       = counts + 2048;         // 512

    prep_kernel<<<1346, 256, 0, stream>>>(x, Wq, Wk, bq, bk, samp,
                                          xh, xl, wh, wl, biascat, counts,
                                          xbc_part);
    projqk_kernel<<<528, 256, 0, stream>>>(xh, xl, wh, wl, biascat,
                                           xbc_part, Wk, bk, samp, counts, kbar,
                                           qh, ql, kh, kl);
    mstat_kernel<<<512, 256, 0, stream>>>(qh, ql, kh, kl, counts, kbar,
                                          bestv, besti);
    ctx_part_kernel<<<dim3(128, 2), 256, 0, stream>>>(qh, ql, kh, kl, x,
                                                      bestv, besti,
                                                      xbar_part, cm, cs);
    ctx_combine_kernel<<<16, 256, 0, stream>>>(xbar_part, cm, cs, Wv, bv, ctx);
    out_kernel<<<dim3(2, 64), 256, 0, stream>>>(ctx, Wo, bo, out);
}